// Round 2
// baseline (13626.523 us; speedup 1.0000x reference)
//
#include <hip/hip_runtime.h>
#include <cmath>

// Problem constants (B=1024 batches, S=200 nodes, E=128, H=8 heads, dh=16)
constexpr int Bn = 1024, Sn = 200, En = 128, Hn = 8, DHn = 16, Tn = 199;
constexpr long long LOGITS_N = (long long)Bn * Tn * Sn;   // 40,755,200
constexpr long long LOGP_OFF = LOGITS_N;                  // [B] log probs
constexpr long long SOL_OFF  = LOGP_OFF + Bn;             // [B][S] solution (as float)

#define NEG_INF (-__builtin_inff())

// ---------------------------------------------------------------------------
// Kernel 1: per-batch query constants.
//   qtop[b] = mean_s(enc[b]) @ Wq_top
//   qh0[b]  = qtop[b] + vl@Wq_mid + vf@Wq_bot     (the full q at t=0)
// ---------------------------------------------------------------------------
__global__ __launch_bounds__(128) void hhat_kernel(
    const float* __restrict__ enc, const float* __restrict__ vl, const float* __restrict__ vf,
    const float* __restrict__ Wq, float* __restrict__ qtop, float* __restrict__ qh0)
{
  const int b = blockIdx.x, e = threadIdx.x;
  const float* p = enc + (size_t)b * Sn * En + e;
  float s = 0.f;
  for (int i = 0; i < Sn; ++i) s += p[(size_t)i * En];
  __shared__ float hl[En];
  hl[e] = s * (1.0f / Sn);
  __syncthreads();
  float qt = 0.f, qm = 0.f, qf = 0.f;
#pragma unroll 8
  for (int i = 0; i < En; ++i) {
    qt += hl[i] * Wq[i * En + e];
    qm += vl[i] * Wq[(En + i) * En + e];
    qf += vf[i] * Wq[(2 * En + i) * En + e];
  }
  qtop[(size_t)b * En + e] = qt;
  qh0[(size_t)b * En + e]  = qt + qm + qf;
}

// ---------------------------------------------------------------------------
// Kernel 2: projections (4 matmuls), register-blocked (16 outputs/thread).
//   K2/V2/KP2 [b][e>>2][s][4]  (decode loads these as coalesced float4)
//   QM        [b][s][e]        (row-major; decode stages whole slice to LDS)
// ---------------------------------------------------------------------------
__global__ __launch_bounds__(256) void proj_kernel(
    const float* __restrict__ enc,
    const float* __restrict__ Wk, const float* __restrict__ Wv,
    const float* __restrict__ Wq, const float* __restrict__ Wp,
    float* __restrict__ K2, float* __restrict__ V2,
    float* __restrict__ QM, float* __restrict__ KP2)
{
  __shared__ float et[32 * En];     // 16 KB tile of enc rows
  __shared__ float wl[En * En];     // 64 KB weight matrix (LDS-cached)
  const int tid = threadIdx.x;
  const size_t r0 = (size_t)blockIdx.x * 32;

  for (int i = tid; i < 32 * En; i += 256) et[i] = enc[r0 * En + i];

  const float* Ws[4] = {Wk, Wv, Wq + (size_t)En * En, Wp};
  const int j = tid & 127, half = tid >> 7;
  for (int m = 0; m < 4; ++m) {
    __syncthreads();                       // protect wl before overwrite (and et after load)
    const float* W = Ws[m];
    for (int i = tid; i < En * En; i += 256) wl[i] = W[i];
    __syncthreads();
    float a[16];
#pragma unroll
    for (int r = 0; r < 16; ++r) a[r] = 0.f;
    for (int e = 0; e < En; e += 4) {
      const float w0 = wl[(e    ) * En + j];
      const float w1 = wl[(e + 1) * En + j];
      const float w2 = wl[(e + 2) * En + j];
      const float w3 = wl[(e + 3) * En + j];
#pragma unroll
      for (int r = 0; r < 16; ++r) {
        const float4 e4 = *(const float4*)&et[(r * 2 + half) * En + e];  // broadcast
        a[r] += e4.x * w0 + e4.y * w1 + e4.z * w2 + e4.w * w3;
      }
    }
#pragma unroll
    for (int r = 0; r < 16; ++r) {
      const size_t rg = r0 + r * 2 + half;
      const int b = (int)(rg / Sn), s = (int)(rg - (size_t)b * Sn);
      if (m == 2) {
        QM[rg * En + j] = a[r];
      } else {
        float* o = (m == 0) ? K2 : (m == 1) ? V2 : KP2;
        o[(((size_t)b * 32 + (j >> 2)) * Sn + s) * 4 + (j & 3)] = a[r];
      }
    }
  }
}

// ---------------------------------------------------------------------------
// Kernel 3: sequential decode, one 512-thread block per batch, 199 steps.
// K, V, k_ptr fragments and Wo columns in REGISTERS (wave = head = e-slice;
// lane owns s in {lane, lane+64, lane+128, lane+192}); QM slice in LDS.
// 3 barriers/step; mask is a per-lane 4-bit register; argmax is computed
// redundantly by every wave so idx needs no broadcast barrier.
// ---------------------------------------------------------------------------
__global__ __launch_bounds__(512) void decode_kernel(
    const float* __restrict__ enc, const float* __restrict__ Wq, const float* __restrict__ Wo,
    const float* __restrict__ K2, const float* __restrict__ V2,
    const float* __restrict__ KP2, const float* __restrict__ QM,
    const float* __restrict__ qtop, const float* __restrict__ qh0,
    float* __restrict__ out)
{
  const int b = blockIdx.x, tid = threadIdx.x;
  const int w = tid >> 6, lane = tid & 63;       // wave w = head w = e-slice [16w,16w+16)
  const int le = lane & 15, q4 = lane >> 4;
  // bit-reversal of 4-bit lane id: d held by this lane after the halving butterfly
  const int dm = ((le & 1) << 3) | ((le & 2) << 1) | ((le & 4) >> 1) | ((le & 8) >> 3);

  __shared__ __align__(16) float qmL[Sn * En];   // 100 KB: enc@Wq_mid, this batch
  __shared__ __align__(16) float ctxp[4 * 36];   // ctx, 32-float groups padded by 4
  __shared__ float part[8 * 257];                // u partials per wave (padded stride)
  __shared__ float uvals[256];
  __shared__ float hqf[En];                      // qtop + first@Wq_bot (qh0 at t=0)
  __shared__ float ebuf[En];

  // ---- prologue: stage QM slice to LDS (coalesced) ----
  {
    const float4* src = (const float4*)(QM + (size_t)b * Sn * En);
    float4* dst = (float4*)qmL;
    for (int i = tid; i < Sn * En / 4; i += 512) dst[i] = src[i];
  }
  if (tid < En) hqf[tid] = qh0[(size_t)b * En + tid];
  if (tid >= 200 && tid < 256) uvals[tid] = NEG_INF;
  if (tid == 0) out[SOL_OFF + (size_t)b * Sn] = 0.f;

  // ---- K/V/KP fragments (coalesced float4: lanes are consecutive s) ----
  float Kr[4][16], Vr[4][16], KPr[4][16];
#pragma unroll
  for (int j = 0; j < 4; ++j) {
    const int s = j * 64 + lane;
    if (s < Sn) {
#pragma unroll
      for (int q = 0; q < 4; ++q) {
        const size_t base = (((size_t)b * 32 + w * 4 + q) * Sn + s) * 4;
        const float4 kv = *(const float4*)(K2 + base);
        const float4 vv = *(const float4*)(V2 + base);
        const float4 pv = *(const float4*)(KP2 + base);
        Kr[j][4*q+0] = kv.x; Kr[j][4*q+1] = kv.y; Kr[j][4*q+2] = kv.z; Kr[j][4*q+3] = kv.w;
        Vr[j][4*q+0] = vv.x; Vr[j][4*q+1] = vv.y; Vr[j][4*q+2] = vv.z; Vr[j][4*q+3] = vv.w;
        KPr[j][4*q+0] = pv.x; KPr[j][4*q+1] = pv.y; KPr[j][4*q+2] = pv.z; KPr[j][4*q+3] = pv.w;
      }
    } else {
#pragma unroll
      for (int d = 0; d < 16; ++d) { Kr[j][d] = 0.f; Vr[j][d] = 0.f; KPr[j][d] = 0.f; }
    }
  }
  // ---- Wo fragment: col = w*16+le, rows q4*32..q4*32+31 ----
  float WoR[32];
  {
    const float* wp = Wo + (size_t)(q4 * 32) * En + (w * DHn + le);
#pragma unroll
    for (int r = 0; r < 32; ++r) WoR[r] = wp[(size_t)r * En];
  }

  // per-lane mask: bit j = node (j*64+lane) visited (or out of range)
  unsigned mreg = (lane == 0 ? 1u : 0u) | (lane >= 8 ? 8u : 0u);
  float logp = 0.f;
  int idx = 0;
  __syncthreads();

  for (int t = 0; t < Tn; ++t) {
    // ================= A: scores + softmax + ctx (wave-local) =================
    float sc4[4] = {0.f, 0.f, 0.f, 0.f};
#pragma unroll
    for (int c = 0; c < 4; ++c) {
      const float4 hv = *(const float4*)&hqf[w * DHn + 4 * c];
      float q0 = hv.x, q1 = hv.y, q2 = hv.z, q3 = hv.w;
      if (t) {
        const float4 qm4 = *(const float4*)&qmL[idx * En + w * DHn + 4 * c];
        q0 += qm4.x; q1 += qm4.y; q2 += qm4.z; q3 += qm4.w;
      }
#pragma unroll
      for (int jj = 0; jj < 4; ++jj)
        sc4[jj] += q0 * Kr[jj][4*c] + q1 * Kr[jj][4*c+1] + q2 * Kr[jj][4*c+2] + q3 * Kr[jj][4*c+3];
    }
    float m = NEG_INF;
#pragma unroll
    for (int jj = 0; jj < 4; ++jj) {
      sc4[jj] = ((mreg >> jj) & 1u) ? NEG_INF : sc4[jj] * 0.25f;   // 1/sqrt(16)
      m = fmaxf(m, sc4[jj]);
    }
#pragma unroll
    for (int off = 1; off < 64; off <<= 1) m = fmaxf(m, __shfl_xor(m, off));
    float ev[4]; float sum = 0.f;
#pragma unroll
    for (int jj = 0; jj < 4; ++jj) { ev[jj] = __expf(sc4[jj] - m); sum += ev[jj]; }
#pragma unroll
    for (int off = 1; off < 64; off <<= 1) sum += __shfl_xor(sum, off);
    const float inv = 1.f / sum;

    float red[16];
#pragma unroll
    for (int d = 0; d < 16; ++d) red[d] = 0.f;
#pragma unroll
    for (int jj = 0; jj < 4; ++jj) {
      const float aj = ev[jj] * inv;
#pragma unroll
      for (int d = 0; d < 16; ++d) red[d] += aj * Vr[jj][d];
    }
    // halving butterfly: 8+4+2+1 shfl, then 2 full-width folds
#pragma unroll
    for (int k = 0; k < 4; ++k) {
      const int off = 1 << k, h = 8 >> k;
#pragma unroll
      for (int i = 0; i < 8; ++i) {
        if (i < h) {
          const bool up = (lane & off) != 0;
          const float send = up ? red[i] : red[i + h];
          const float keep = up ? red[i + h] : red[i];
          red[i] = keep + __shfl_xor(send, off);
        }
      }
    }
    red[0] += __shfl_xor(red[0], 16);
    red[0] += __shfl_xor(red[0], 32);
    if (lane < 16) {
      const int d = w * DHn + dm;
      ctxp[(d >> 5) * 36 + (d & 31)] = red[0];
    }
    __syncthreads();   // b1: ctxp complete

    // ============ B: octx col (Wo in regs, padded-broadcast ctx reads) ============
    float p = 0.f;
#pragma unroll
    for (int c = 0; c < 8; ++c) {
      const float4 cv = *(const float4*)&ctxp[q4 * 36 + 4 * c];
      p += cv.x * WoR[4*c] + cv.y * WoR[4*c+1] + cv.z * WoR[4*c+2] + cv.w * WoR[4*c+3];
    }
    p += __shfl_xor(p, 16);
    p += __shfl_xor(p, 32);          // all lanes: octx[w*16+le]

    // ============ C: u partials over this wave's e-slice (all registers) ============
    float up[4] = {0.f, 0.f, 0.f, 0.f};
#pragma unroll
    for (int d = 0; d < 16; ++d) {
      const float od = __shfl(p, d);  // octx[w*16+d] from lane d
#pragma unroll
      for (int jj = 0; jj < 4; ++jj) up[jj] += od * KPr[jj][d];
    }
#pragma unroll
    for (int jj = 0; jj < 4; ++jj) part[w * 257 + jj * 64 + lane] = up[jj];
    __syncthreads();   // b2: partials complete

    // ============ D: finalize u, store logits (waves 0-3) ============
    if (tid < Sn) {
      float u = 0.f;
#pragma unroll
      for (int ww = 0; ww < 8; ++ww) u += part[ww * 257 + tid];
      const float e2 = __expf(u * (2.f * 0.08838834764831845f));   // 2x/sqrt(128)
      const float uu = 10.f * (1.f - 2.f / (e2 + 1.f));            // 10*tanh
      out[((size_t)b * Tn + t) * Sn + tid] = uu;                   // raw (unmasked) logits
      uvals[tid] = uu;
    }
    __syncthreads();   // b3: uvals complete

    // ============ E: redundant argmax in every wave; logp in wave 0 ============
    float bv = NEG_INF; int bi = 1 << 30;
    float vk[4];
#pragma unroll
    for (int k = 0; k < 4; ++k) {
      const int s = k * 64 + lane;
      const float v = ((mreg >> k) & 1u) ? NEG_INF : uvals[s];
      vk[k] = v;
      if (v > bv || (v == bv && s < bi)) { bv = v; bi = s; }
    }
#pragma unroll
    for (int off = 1; off < 64; off <<= 1) {
      const float ov = __shfl_xor(bv, off); const int oi = __shfl_xor(bi, off);
      if (ov > bv || (ov == bv && oi < bi)) { bv = ov; bi = oi; }
    }
    idx = bi;
    if ((idx & 63) == lane) mreg |= 1u << (idx >> 6);
    if (w == 0) {
      float s2 = 0.f;
#pragma unroll
      for (int k = 0; k < 4; ++k) s2 += __expf(vk[k] - bv);   // exp(-inf)=0 for masked
#pragma unroll
      for (int off = 1; off < 64; off <<= 1) s2 += __shfl_xor(s2, off);
      if (lane == 0) {
        logp += __logf(s2);   // ce = log(sum(exp(u - max)))
        out[SOL_OFF + (size_t)b * Sn + t + 1] = (float)bi;
      }
    }

    if (t == 0) {
      // first = enc[b, idx0]: hqf = qtop + first@Wq_bot (once)
      if (tid < En) ebuf[tid] = enc[((size_t)b * Sn + idx) * En + tid];
      __syncthreads();
      float pb = 0.f;
#pragma unroll 8
      for (int r = 0; r < 32; ++r)
        pb += ebuf[q4 * 32 + r] * Wq[(size_t)(2 * En + q4 * 32 + r) * En + (w * DHn + le)];
      pb += __shfl_xor(pb, 16);
      pb += __shfl_xor(pb, 32);
      if (lane < 16) hqf[w * DHn + le] = qtop[(size_t)b * En + w * DHn + le] + pb;
      __syncthreads();
    }
  }
  if (tid == 0) out[LOGP_OFF + b] = logp;
}

// ---------------------------------------------------------------------------
extern "C" void kernel_launch(void* const* d_in, const int* in_sizes, int n_in,
                              void* d_out, int out_size, void* d_ws, size_t ws_size,
                              hipStream_t stream)
{
  const float* enc = (const float*)d_in[0];
  // d_in[1] demands, d_in[2] capacities: unused by the forward pass
  const float* vl  = (const float*)d_in[3];
  const float* vf  = (const float*)d_in[4];
  const float* Wq  = (const float*)d_in[5];
  const float* Wk  = (const float*)d_in[6];
  const float* Wv  = (const float*)d_in[7];
  const float* Wo  = (const float*)d_in[8];
  const float* Wp  = (const float*)d_in[9];
  float* out = (float*)d_out;

  float* ws   = (float*)d_ws;
  const size_t BSE = (size_t)Bn * Sn * En;
  float* K2   = ws;                 // [B][32][S][4]
  float* V2   = K2  + BSE;          // [B][32][S][4]
  float* QM   = V2  + BSE;          // [B][S][E]   enc@Wq_mid
  float* KP2  = QM  + BSE;          // [B][32][S][4]
  float* qtop = KP2 + BSE;          // [B][E]
  float* qh0  = qtop + (size_t)Bn * En;  // [B][E]

  hipLaunchKernelGGL(hhat_kernel, dim3(Bn), dim3(En), 0, stream, enc, vl, vf, Wq, qtop, qh0);
  hipLaunchKernelGGL(proj_kernel, dim3((Bn * Sn) / 32), dim3(256), 0, stream,
                     enc, Wk, Wv, Wq, Wp, K2, V2, QM, KP2);
  hipLaunchKernelGGL(decode_kernel, dim3(Bn), dim3(512), 0, stream,
                     enc, Wq, Wo, K2, V2, KP2, QM, qtop, qh0, out);
}

// Round 4
// 9724.413 us; speedup vs baseline: 1.4013x; 1.4013x over previous
//
#include <hip/hip_runtime.h>
#include <cmath>

// Problem constants (B=1024 batches, S=200 nodes, E=128, H=8 heads, dh=16)
constexpr int Bn = 1024, Sn = 200, En = 128, Hn = 8, DHn = 16, Tn = 199;
constexpr long long LOGITS_N = (long long)Bn * Tn * Sn;   // 40,755,200
constexpr long long LOGP_OFF = LOGITS_N;                  // [B] log probs
constexpr long long SOL_OFF  = LOGP_OFF + Bn;             // [B][S] solution (as float)

#define NEG_INF (-__builtin_inff())

// ---------------------------------------------------------------------------
// Kernel 1: per-batch query constants.
//   qtop[b] = mean_s(enc[b]) @ Wq_top
//   qh0[b]  = qtop[b] + vl@Wq_mid + vf@Wq_bot     (the full q at t=0)
// ---------------------------------------------------------------------------
__global__ __launch_bounds__(128) void hhat_kernel(
    const float* __restrict__ enc, const float* __restrict__ vl, const float* __restrict__ vf,
    const float* __restrict__ Wq, float* __restrict__ qtop, float* __restrict__ qh0)
{
  const int b = blockIdx.x, e = threadIdx.x;
  const float* p = enc + (size_t)b * Sn * En + e;
  float s = 0.f;
  for (int i = 0; i < Sn; ++i) s += p[(size_t)i * En];
  __shared__ float hl[En];
  hl[e] = s * (1.0f / Sn);
  __syncthreads();
  float qt = 0.f, qm = 0.f, qf = 0.f;
#pragma unroll 8
  for (int i = 0; i < En; ++i) {
    qt += hl[i] * Wq[i * En + e];
    qm += vl[i] * Wq[(En + i) * En + e];
    qf += vf[i] * Wq[(2 * En + i) * En + e];
  }
  qtop[(size_t)b * En + e] = qt;
  qh0[(size_t)b * En + e]  = qt + qm + qf;
}

// ---------------------------------------------------------------------------
// Kernel 1b: Wfold[e][i] = sum_k Wp[e][k] * Wo[i][k]   (fold Wo into kp:
//   u[s] = octx . kp_s = ctx . (enc_s @ Wp @ Wo^T) = ctx . (enc_s @ Wfold))
// ---------------------------------------------------------------------------
__global__ __launch_bounds__(128) void wfold_kernel(
    const float* __restrict__ Wp, const float* __restrict__ Wo, float* __restrict__ Wfold)
{
  const int e = blockIdx.x, i = threadIdx.x;
  __shared__ float wpr[En];
  wpr[i] = Wp[e * En + i];
  __syncthreads();
  float a = 0.f;
#pragma unroll 8
  for (int k = 0; k < En; ++k) a += wpr[k] * Wo[i * En + k];
  Wfold[e * En + i] = a;
}

// ---------------------------------------------------------------------------
// Kernel 2: projections (4 matmuls), persistent blocks: 256 blocks, each
// stages each 64KB weight ONCE and streams 25 row-tiles of enc through it.
// All outputs in decode-friendly layout [b][e>>2][s][4] (float4 per s).
// ---------------------------------------------------------------------------
constexpr int PTILES = 25;   // 256 blocks * 25 tiles * 32 rows = 204800 = B*S
__global__ __launch_bounds__(256) void proj_kernel(
    const float* __restrict__ enc,
    const float* __restrict__ Wk, const float* __restrict__ Wv,
    const float* __restrict__ Wq, const float* __restrict__ Wfold,
    float* __restrict__ K2, float* __restrict__ V2,
    float* __restrict__ QM, float* __restrict__ KP2)
{
  __shared__ __align__(16) float wl[En * En];   // 64 KB weight (staged once per m)
  __shared__ __align__(16) float et[32 * 132];  // 16.5 KB enc tile, padded stride 132
  const int tid = threadIdx.x;
  const int sl = tid & 15;             // s-lane (16 consecutive rows per inst)
  const int jg = tid >> 4;             // 16 j-groups of 8 columns

  for (int m = 0; m < 4; ++m) {
    const float* W = (m == 0) ? Wk : (m == 1) ? Wv : (m == 2) ? (Wq + (size_t)En * En) : Wfold;
    float* O = (m == 0) ? K2 : (m == 1) ? V2 : (m == 2) ? QM : KP2;
    __syncthreads();                   // protect wl vs previous m's compute
    {
      const float4* src = (const float4*)W;
      float4* dst = (float4*)wl;
      for (int i = tid; i < En * En / 4; i += 256) dst[i] = src[i];
    }
    for (int tile = 0; tile < PTILES; ++tile) {
      const size_t r0 = ((size_t)blockIdx.x * PTILES + tile) * 32;
      __syncthreads();                 // et reuse (and wl ready on first tile)
      {
        const int rr = tid >> 3, e0 = (tid & 7) * 16;
        const float4* src = (const float4*)(enc + (r0 + rr) * En + e0);
        float4* dst = (float4*)&et[rr * 132 + e0];
        dst[0] = src[0]; dst[1] = src[1]; dst[2] = src[2]; dst[3] = src[3];
      }
      __syncthreads();
      float a0[8], a1[8];
#pragma unroll
      for (int x = 0; x < 8; ++x) { a0[x] = 0.f; a1[x] = 0.f; }
#pragma unroll 4
      for (int e = 0; e < En; ++e) {
        const float4 wa = *(const float4*)&wl[e * En + jg * 8];
        const float4 wb = *(const float4*)&wl[e * En + jg * 8 + 4];
        const float ea = et[sl * 132 + e];          // 2-way broadcast groups
        const float eb = et[(sl + 16) * 132 + e];
        a0[0] += ea * wa.x; a0[1] += ea * wa.y; a0[2] += ea * wa.z; a0[3] += ea * wa.w;
        a0[4] += ea * wb.x; a0[5] += ea * wb.y; a0[6] += ea * wb.z; a0[7] += ea * wb.w;
        a1[0] += eb * wa.x; a1[1] += eb * wa.y; a1[2] += eb * wa.z; a1[3] += eb * wa.w;
        a1[4] += eb * wb.x; a1[5] += eb * wb.y; a1[6] += eb * wb.z; a1[7] += eb * wb.w;
      }
      // stores: 16 consecutive s per 16-lane group -> 256B contiguous segments
#pragma unroll
      for (int k = 0; k < 2; ++k) {
        const size_t rg = r0 + sl + 16 * k;
        const int bb = (int)(rg / Sn), ss = (int)(rg - (size_t)bb * Sn);
        const float* a = k ? a1 : a0;
        float4 v0 = make_float4(a[0], a[1], a[2], a[3]);
        float4 v1 = make_float4(a[4], a[5], a[6], a[7]);
        *(float4*)(O + (((size_t)bb * 32 + 2 * jg    ) * Sn + ss) * 4) = v0;
        *(float4*)(O + (((size_t)bb * 32 + 2 * jg + 1) * Sn + ss) * 4) = v1;
      }
    }
  }
}

// ---------------------------------------------------------------------------
// Kernel 3: sequential decode, one 1024-thread block (16 waves) per batch.
// Wave pair (2h, 2h+1) = head h; each wave owns an s-half (128 nodes).
// Registers/thread: Kr[2][16]+Vr[2][16]+KPr[4][8] = 96 floats -> fits the
// 128-VGPR cap at 4 waves/SIMD (R2's spill disaster: 224 floats @ cap 128).
// Cross-wave softmax via deferred normalization (m, sum, unnormalized ctx).
// 3 barriers/step.
// ---------------------------------------------------------------------------
__global__ __launch_bounds__(1024) void decode_kernel(
    const float* __restrict__ enc, const float* __restrict__ Wq,
    const float* __restrict__ K2, const float* __restrict__ V2,
    const float* __restrict__ KP2, const float* __restrict__ QM,
    const float* __restrict__ qtop, const float* __restrict__ qh0,
    float* __restrict__ out)
{
  const int b = blockIdx.x, tid = threadIdx.x;
  const int w = tid >> 6, lane = tid & 63;
  const int h = w >> 1, p = w & 1;     // head, s-half

  __shared__ __align__(16) float qmL[32 * Sn * 4];  // 100 KB enc@Wq_mid, g-major
  __shared__ __align__(16) float part[16 * 256];    // 16 KB u partials
  __shared__ float ctxpart[16][16];                 // per-wave unnormalized ctx
  __shared__ float msA[16], msS[16];                // per-wave max / expsum
  __shared__ float uvals[256];
  __shared__ __align__(16) float hqf[En];           // qtop + first@Wq_bot
  __shared__ float ebuf[En];

  // ---- prologue ----
  {
    const float4* src = (const float4*)(QM + (size_t)b * (Sn * En));
    float4* dst = (float4*)qmL;
    for (int i = tid; i < Sn * En / 4; i += 1024) dst[i] = src[i];
  }
  if (tid < En) hqf[tid] = qh0[(size_t)b * En + tid];   // q at t=0
  if (tid >= 200 && tid < 256) uvals[tid] = NEG_INF;
  if (tid == 0) out[SOL_OFF + (size_t)b * Sn] = 0.f;

  float Kr[2][16], Vr[2][16];
#pragma unroll
  for (int j = 0; j < 2; ++j) {
    const int s = 128 * p + 64 * j + lane;
    if (s < Sn) {
#pragma unroll
      for (int q = 0; q < 4; ++q) {
        const size_t base = (((size_t)b * 32 + 4 * h + q) * Sn + s) * 4;
        const float4 kv = *(const float4*)(K2 + base);
        const float4 vv = *(const float4*)(V2 + base);
        Kr[j][4*q+0] = kv.x; Kr[j][4*q+1] = kv.y; Kr[j][4*q+2] = kv.z; Kr[j][4*q+3] = kv.w;
        Vr[j][4*q+0] = vv.x; Vr[j][4*q+1] = vv.y; Vr[j][4*q+2] = vv.z; Vr[j][4*q+3] = vv.w;
      }
    } else {
#pragma unroll
      for (int d = 0; d < 16; ++d) { Kr[j][d] = 0.f; Vr[j][d] = 0.f; }
    }
  }
  float KPr[4][8];                      // i-slice [8w, 8w+8), s in {64k+lane}
#pragma unroll
  for (int k = 0; k < 4; ++k) {
    const int s = 64 * k + lane;
    if (s < Sn) {
#pragma unroll
      for (int a = 0; a < 2; ++a) {
        const float4 v = *(const float4*)(KP2 + (((size_t)b * 32 + 2 * w + a) * Sn + s) * 4);
        KPr[k][4*a+0] = v.x; KPr[k][4*a+1] = v.y; KPr[k][4*a+2] = v.z; KPr[k][4*a+3] = v.w;
      }
    } else {
#pragma unroll
      for (int d = 0; d < 8; ++d) KPr[k][d] = 0.f;
    }
  }

  // per-lane mask: bit k = node (64k+lane) visited / out of range
  unsigned mreg = (lane == 0 ? 1u : 0u) | (lane >= 8 ? 8u : 0u);
  float logp = 0.f;
  int idx = 0;
  __syncthreads();

  for (int t = 0; t < Tn; ++t) {
    // ===== A: scores + per-wave softmax stats + unnormalized ctx partial =====
    float sc0 = 0.f, sc1 = 0.f;        // s = 128p+lane, 128p+64+lane
#pragma unroll
    for (int c = 0; c < 4; ++c) {
      float4 qc = *(const float4*)&hqf[16 * h + 4 * c];
      if (t) {
        const float4 qm = ((const float4*)qmL)[(4 * h + c) * Sn + idx];  // broadcast
        qc.x += qm.x; qc.y += qm.y; qc.z += qm.z; qc.w += qm.w;
      }
      sc0 += qc.x*Kr[0][4*c] + qc.y*Kr[0][4*c+1] + qc.z*Kr[0][4*c+2] + qc.w*Kr[0][4*c+3];
      sc1 += qc.x*Kr[1][4*c] + qc.y*Kr[1][4*c+1] + qc.z*Kr[1][4*c+2] + qc.w*Kr[1][4*c+3];
    }
    const bool mk0 = (mreg >> (2 * p)) & 1u, mk1 = (mreg >> (2 * p + 1)) & 1u;
    sc0 = mk0 ? NEG_INF : sc0 * 0.25f;      // 1/sqrt(16)
    sc1 = mk1 ? NEG_INF : sc1 * 0.25f;
    float m = fmaxf(sc0, sc1);
#pragma unroll
    for (int off = 1; off < 64; off <<= 1) m = fmaxf(m, __shfl_xor(m, off));
    const float ev0 = mk0 ? 0.f : __expf(sc0 - m);   // explicit 0 avoids inf-inf
    const float ev1 = mk1 ? 0.f : __expf(sc1 - m);
    float ssum = ev0 + ev1;
#pragma unroll
    for (int off = 1; off < 64; off <<= 1) ssum += __shfl_xor(ssum, off);
    // unnormalized ctx partial, halving butterfly in 2 chunks of 8 (reg-lean)
#pragma unroll
    for (int ch = 0; ch < 2; ++ch) {
      float red[8];
#pragma unroll
      for (int d = 0; d < 8; ++d) red[d] = ev0 * Vr[0][8*ch+d] + ev1 * Vr[1][8*ch+d];
#pragma unroll
      for (int k = 0; k < 3; ++k) {
        const int off = 1 << k, hh = 4 >> k;
#pragma unroll
        for (int i = 0; i < 4; ++i) if (i < hh) {
          const bool up = (lane & off) != 0;
          const float send = up ? red[i] : red[i + hh];
          const float keep = up ? red[i + hh] : red[i];
          red[i] = keep + __shfl_xor(send, off);
        }
      }
      red[0] += __shfl_xor(red[0], 8);
      red[0] += __shfl_xor(red[0], 16);
      red[0] += __shfl_xor(red[0], 32);
      if (lane < 8) {
        const int dm3 = ((lane & 1) << 2) | (lane & 2) | ((lane & 4) >> 2);
        ctxpart[w][8 * ch + dm3] = red[0];
      }
    }
    if (lane == 0) { msA[w] = m; msS[w] = ssum; }
    __syncthreads();   // b1

    // ===== C: combine pair softmax + u partials over i-slice (registers) =====
    {
      const float m0 = msA[2 * h], m1 = msA[2 * h + 1];
      const float M = fmaxf(m0, m1);
      float c0 = __expf(m0 - M), c1 = __expf(m1 - M);     // exp(-inf)=0
      const float inv = 1.f / (c0 * msS[2 * h] + c1 * msS[2 * h + 1]);
      c0 *= inv; c1 *= inv;
      float u0 = 0.f, u1 = 0.f, u2 = 0.f, u3 = 0.f;
#pragma unroll
      for (int j = 0; j < 8; ++j) {
        const int d = (p << 3) + j;                       // ctx idx = 16h + d = 8w+j
        const float cx = c0 * ctxpart[2 * h][d] + c1 * ctxpart[2 * h + 1][d];
        u0 += cx * KPr[0][j]; u1 += cx * KPr[1][j];
        u2 += cx * KPr[2][j]; u3 += cx * KPr[3][j];
      }
      part[w * 256 +       lane] = u0;
      part[w * 256 +  64 + lane] = u1;
      part[w * 256 + 128 + lane] = u2;
      part[w * 256 + 192 + lane] = u3;
    }
    __syncthreads();   // b2

    // ===== D: finalize u = 10*tanh(dot/sqrt(128)) =====
    float uu = 0.f;
    if (tid < Sn) {
      float u = 0.f;
#pragma unroll
      for (int ww = 0; ww < 16; ++ww) u += part[ww * 256 + tid];
      const float e2 = __expf(u * 0.17677669529663687f);   // 2/sqrt(128)
      uu = 10.f - 20.f / (e2 + 1.f);
      uvals[tid] = uu;
    }
    __syncthreads();   // b3

    // ===== E: redundant per-wave argmax (no broadcast barrier needed) =====
    float bv = NEG_INF; int bi = 1 << 30;
    float vk[4];
#pragma unroll
    for (int k = 0; k < 4; ++k) {
      const int s = 64 * k + lane;
      const float v = ((mreg >> k) & 1u) ? NEG_INF : uvals[s];
      vk[k] = v;
      if (v > bv || (v == bv && s < bi)) { bv = v; bi = s; }
    }
#pragma unroll
    for (int off = 1; off < 64; off <<= 1) {
      const float ov = __shfl_xor(bv, off); const int oi = __shfl_xor(bi, off);
      if (ov > bv || (ov == bv && oi < bi)) { bv = ov; bi = oi; }
    }
    idx = bi;
    if ((idx & 63) == lane) mreg |= 1u << (idx >> 6);
    // global stores AFTER argmax: their vmcnt drain lands on next b1, off path
    if (tid < Sn) out[((size_t)b * Tn + t) * Sn + tid] = uu;  // raw logits
    if (w == 0) {
      float s2 = 0.f;
#pragma unroll
      for (int k = 0; k < 4; ++k) s2 += __expf(vk[k] - bv);   // exp(-inf)=0
#pragma unroll
      for (int off = 1; off < 64; off <<= 1) s2 += __shfl_xor(s2, off);
      if (lane == 0) {
        logp += __logf(s2);      // ce = log(sum(exp(u - max)))
        out[SOL_OFF + (size_t)b * Sn + t + 1] = (float)bi;
      }
    }

    if (t == 0) {     // hqf = qtop + first@Wq_bot (once; first = enc[b, idx0])
      if (tid < En) ebuf[tid] = enc[((size_t)b * Sn + idx) * En + tid];
      __syncthreads();
      {
        const int seg = tid >> 7, e = tid & 127;
        float pb = 0.f;
#pragma unroll
        for (int r = 0; r < 16; ++r)
          pb += ebuf[seg * 16 + r] * Wq[(size_t)(2 * En + seg * 16 + r) * En + e];
        part[seg * 256 + e] = pb;
      }
      __syncthreads();
      if (tid < En) {
        float acc2 = qtop[(size_t)b * En + tid];
#pragma unroll
        for (int sg = 0; sg < 8; ++sg) acc2 += part[sg * 256 + tid];
        hqf[tid] = acc2;
      }
      __syncthreads();
    }
  }
  if (tid == 0) out[LOGP_OFF + b] = logp;
}

// ---------------------------------------------------------------------------
extern "C" void kernel_launch(void* const* d_in, const int* in_sizes, int n_in,
                              void* d_out, int out_size, void* d_ws, size_t ws_size,
                              hipStream_t stream)
{
  const float* enc = (const float*)d_in[0];
  // d_in[1] demands, d_in[2] capacities: unused by the forward pass
  const float* vl  = (const float*)d_in[3];
  const float* vf  = (const float*)d_in[4];
  const float* Wq  = (const float*)d_in[5];
  const float* Wk  = (const float*)d_in[6];
  const float* Wv  = (const float*)d_in[7];
  const float* Wo  = (const float*)d_in[8];
  const float* Wp  = (const float*)d_in[9];
  float* out = (float*)d_out;

  float* ws    = (float*)d_ws;
  const size_t BSE = (size_t)Bn * Sn * En;
  float* K2    = ws;                  // [B][32][S][4]
  float* V2    = K2  + BSE;           // [B][32][S][4]
  float* QM    = V2  + BSE;           // [B][32][S][4]  enc@Wq_mid (g-major)
  float* KP2   = QM  + BSE;           // [B][32][S][4]  enc@(Wp@Wo^T)
  float* qtop  = KP2 + BSE;           // [B][E]
  float* qh0   = qtop + (size_t)Bn * En;   // [B][E]
  float* Wfold = qh0  + (size_t)Bn * En;   // [E][E]

  hipLaunchKernelGGL(hhat_kernel, dim3(Bn), dim3(En), 0, stream, enc, vl, vf, Wq, qtop, qh0);
  hipLaunchKernelGGL(wfold_kernel, dim3(En), dim3(En), 0, stream, Wp, Wo, Wfold);
  hipLaunchKernelGGL(proj_kernel, dim3(256), dim3(256), 0, stream,
                     enc, Wk, Wv, Wq, Wfold, K2, V2, QM, KP2);
  hipLaunchKernelGGL(decode_kernel, dim3(Bn), dim3(1024), 0, stream,
                     enc, Wq, K2, V2, KP2, QM, qtop, qh0, out);
}

// Round 5
// 9716.653 us; speedup vs baseline: 1.4024x; 1.0008x over previous
//
#include <hip/hip_runtime.h>
#include <cmath>

// Problem constants (B=1024 batches, S=200 nodes, E=128, H=8 heads, dh=16)
constexpr int Bn = 1024, Sn = 200, En = 128, Hn = 8, DHn = 16, Tn = 199;
constexpr long long LOGITS_N = (long long)Bn * Tn * Sn;   // 40,755,200
constexpr long long LOGP_OFF = LOGITS_N;                  // [B] log probs
constexpr long long SOL_OFF  = LOGP_OFF + Bn;             // [B][S] solution (as float)

#define NEG_INF (-__builtin_inff())

// ---------------------------------------------------------------------------
// Kernel 1: per-batch query constants.
//   qtop[b] = mean_s(enc[b]) @ Wq_top
//   qh0[b]  = qtop[b] + vl@Wq_mid + vf@Wq_bot     (the full q at t=0)
// ---------------------------------------------------------------------------
__global__ __launch_bounds__(128) void hhat_kernel(
    const float* __restrict__ enc, const float* __restrict__ vl, const float* __restrict__ vf,
    const float* __restrict__ Wq, float* __restrict__ qtop, float* __restrict__ qh0)
{
  const int b = blockIdx.x, e = threadIdx.x;
  const float* p = enc + (size_t)b * Sn * En + e;
  float s = 0.f;
  for (int i = 0; i < Sn; ++i) s += p[(size_t)i * En];
  __shared__ float hl[En];
  hl[e] = s * (1.0f / Sn);
  __syncthreads();
  float qt = 0.f, qm = 0.f, qf = 0.f;
#pragma unroll 8
  for (int i = 0; i < En; ++i) {
    qt += hl[i] * Wq[i * En + e];
    qm += vl[i] * Wq[(En + i) * En + e];
    qf += vf[i] * Wq[(2 * En + i) * En + e];
  }
  qtop[(size_t)b * En + e] = qt;
  qh0[(size_t)b * En + e]  = qt + qm + qf;
}

// ---------------------------------------------------------------------------
// Kernel 1b: Wfold[e][i] = sum_k Wp[e][k] * Wo[i][k]   (fold Wo into kp:
//   u[s] = octx . kp_s = ctx . (enc_s @ Wp @ Wo^T) = ctx . (enc_s @ Wfold))
// ---------------------------------------------------------------------------
__global__ __launch_bounds__(128) void wfold_kernel(
    const float* __restrict__ Wp, const float* __restrict__ Wo, float* __restrict__ Wfold)
{
  const int e = blockIdx.x, i = threadIdx.x;
  __shared__ float wpr[En];
  wpr[i] = Wp[e * En + i];
  __syncthreads();
  float a = 0.f;
#pragma unroll 8
  for (int k = 0; k < En; ++k) a += wpr[k] * Wo[i * En + k];
  Wfold[e * En + i] = a;
}

// ---------------------------------------------------------------------------
// Kernel 2: projections (4 matmuls), persistent blocks: 256 blocks, each
// stages each 64KB weight ONCE and streams 25 row-tiles of enc through it.
// All outputs in decode-friendly layout [b][e>>2][s][4] (float4 per s).
// ---------------------------------------------------------------------------
constexpr int PTILES = 25;   // 256 blocks * 25 tiles * 32 rows = 204800 = B*S
__global__ __launch_bounds__(256) void proj_kernel(
    const float* __restrict__ enc,
    const float* __restrict__ Wk, const float* __restrict__ Wv,
    const float* __restrict__ Wq, const float* __restrict__ Wfold,
    float* __restrict__ K2, float* __restrict__ V2,
    float* __restrict__ QM, float* __restrict__ KP2)
{
  __shared__ __align__(16) float wl[En * En];   // 64 KB weight (staged once per m)
  __shared__ __align__(16) float et[32 * 132];  // 16.5 KB enc tile, padded stride 132
  const int tid = threadIdx.x;
  const int sl = tid & 15;             // s-lane (16 consecutive rows per inst)
  const int jg = tid >> 4;             // 16 j-groups of 8 columns

  for (int m = 0; m < 4; ++m) {
    const float* W = (m == 0) ? Wk : (m == 1) ? Wv : (m == 2) ? (Wq + (size_t)En * En) : Wfold;
    float* O = (m == 0) ? K2 : (m == 1) ? V2 : (m == 2) ? QM : KP2;
    __syncthreads();                   // protect wl vs previous m's compute
    {
      const float4* src = (const float4*)W;
      float4* dst = (float4*)wl;
      for (int i = tid; i < En * En / 4; i += 256) dst[i] = src[i];
    }
    for (int tile = 0; tile < PTILES; ++tile) {
      const size_t r0 = ((size_t)blockIdx.x * PTILES + tile) * 32;
      __syncthreads();                 // et reuse (and wl ready on first tile)
      {
        const int rr = tid >> 3, e0 = (tid & 7) * 16;
        const float4* src = (const float4*)(enc + (r0 + rr) * En + e0);
        float4* dst = (float4*)&et[rr * 132 + e0];
        dst[0] = src[0]; dst[1] = src[1]; dst[2] = src[2]; dst[3] = src[3];
      }
      __syncthreads();
      float a0[8], a1[8];
#pragma unroll
      for (int x = 0; x < 8; ++x) { a0[x] = 0.f; a1[x] = 0.f; }
#pragma unroll 4
      for (int e = 0; e < En; ++e) {
        const float4 wa = *(const float4*)&wl[e * En + jg * 8];
        const float4 wb = *(const float4*)&wl[e * En + jg * 8 + 4];
        const float ea = et[sl * 132 + e];          // 2-way broadcast groups
        const float eb = et[(sl + 16) * 132 + e];
        a0[0] += ea * wa.x; a0[1] += ea * wa.y; a0[2] += ea * wa.z; a0[3] += ea * wa.w;
        a0[4] += ea * wb.x; a0[5] += ea * wb.y; a0[6] += ea * wb.z; a0[7] += ea * wb.w;
        a1[0] += eb * wa.x; a1[1] += eb * wa.y; a1[2] += eb * wa.z; a1[3] += eb * wa.w;
        a1[4] += eb * wb.x; a1[5] += eb * wb.y; a1[6] += eb * wb.z; a1[7] += eb * wb.w;
      }
      // stores: 16 consecutive s per 16-lane group -> 256B contiguous segments
#pragma unroll
      for (int k = 0; k < 2; ++k) {
        const size_t rg = r0 + sl + 16 * k;
        const int bb = (int)(rg / Sn), ss = (int)(rg - (size_t)bb * Sn);
        const float* a = k ? a1 : a0;
        float4 v0 = make_float4(a[0], a[1], a[2], a[3]);
        float4 v1 = make_float4(a[4], a[5], a[6], a[7]);
        *(float4*)(O + (((size_t)bb * 32 + 2 * jg    ) * Sn + ss) * 4) = v0;
        *(float4*)(O + (((size_t)bb * 32 + 2 * jg + 1) * Sn + ss) * 4) = v1;
      }
    }
  }
}

// ---------------------------------------------------------------------------
// Kernel 3: sequential decode, one 1024-thread block (16 waves) per batch.
// Wave pair (2h, 2h+1) = head h; each wave owns an s-half (128 nodes).
// Registers/thread: Kr[2][16]+Vr[2][16]+KPr[4][8] = 96 floats.
// __launch_bounds__(1024, 4): min 4 waves/EU -> VGPR budget 128. LDS (122KB)
// already limits to 1 block/CU = 4 waves/EU, so this costs no occupancy.
// (R4: default heuristic budgeted 64 VGPRs for unreachable 8 waves/EU ->
//  full spill of K/V/KP, 15.4 GB scratch FETCH.)
// Cross-wave softmax via deferred normalization (m, sum, unnormalized ctx).
// 3 barriers/step.
// ---------------------------------------------------------------------------
__global__ __launch_bounds__(1024, 4) void decode_kernel(
    const float* __restrict__ enc, const float* __restrict__ Wq,
    const float* __restrict__ K2, const float* __restrict__ V2,
    const float* __restrict__ KP2, const float* __restrict__ QM,
    const float* __restrict__ qtop, const float* __restrict__ qh0,
    float* __restrict__ out)
{
  const int b = blockIdx.x, tid = threadIdx.x;
  const int w = tid >> 6, lane = tid & 63;
  const int h = w >> 1, p = w & 1;     // head, s-half

  __shared__ __align__(16) float qmL[32 * Sn * 4];  // 100 KB enc@Wq_mid, g-major
  __shared__ __align__(16) float part[16 * 256];    // 16 KB u partials
  __shared__ float ctxpart[16][16];                 // per-wave unnormalized ctx
  __shared__ float msA[16], msS[16];                // per-wave max / expsum
  __shared__ float uvals[256];
  __shared__ __align__(16) float hqf[En];           // qtop + first@Wq_bot
  __shared__ float ebuf[En];

  // ---- prologue ----
  {
    const float4* src = (const float4*)(QM + (size_t)b * (Sn * En));
    float4* dst = (float4*)qmL;
    for (int i = tid; i < Sn * En / 4; i += 1024) dst[i] = src[i];
  }
  if (tid < En) hqf[tid] = qh0[(size_t)b * En + tid];   // q at t=0
  if (tid >= 200 && tid < 256) uvals[tid] = NEG_INF;
  if (tid == 0) out[SOL_OFF + (size_t)b * Sn] = 0.f;

  float Kr[2][16], Vr[2][16];
#pragma unroll
  for (int j = 0; j < 2; ++j) {
    const int s = 128 * p + 64 * j + lane;
    if (s < Sn) {
#pragma unroll
      for (int q = 0; q < 4; ++q) {
        const size_t base = (((size_t)b * 32 + 4 * h + q) * Sn + s) * 4;
        const float4 kv = *(const float4*)(K2 + base);
        const float4 vv = *(const float4*)(V2 + base);
        Kr[j][4*q+0] = kv.x; Kr[j][4*q+1] = kv.y; Kr[j][4*q+2] = kv.z; Kr[j][4*q+3] = kv.w;
        Vr[j][4*q+0] = vv.x; Vr[j][4*q+1] = vv.y; Vr[j][4*q+2] = vv.z; Vr[j][4*q+3] = vv.w;
      }
    } else {
#pragma unroll
      for (int d = 0; d < 16; ++d) { Kr[j][d] = 0.f; Vr[j][d] = 0.f; }
    }
  }
  float KPr[4][8];                      // i-slice [8w, 8w+8), s in {64k+lane}
#pragma unroll
  for (int k = 0; k < 4; ++k) {
    const int s = 64 * k + lane;
    if (s < Sn) {
#pragma unroll
      for (int a = 0; a < 2; ++a) {
        const float4 v = *(const float4*)(KP2 + (((size_t)b * 32 + 2 * w + a) * Sn + s) * 4);
        KPr[k][4*a+0] = v.x; KPr[k][4*a+1] = v.y; KPr[k][4*a+2] = v.z; KPr[k][4*a+3] = v.w;
      }
    } else {
#pragma unroll
      for (int d = 0; d < 8; ++d) KPr[k][d] = 0.f;
    }
  }

  // per-lane mask: bit k = node (64k+lane) visited / out of range
  unsigned mreg = (lane == 0 ? 1u : 0u) | (lane >= 8 ? 8u : 0u);
  float logp = 0.f;
  int idx = 0;
  __syncthreads();

  for (int t = 0; t < Tn; ++t) {
    // ===== A: scores + per-wave softmax stats + unnormalized ctx partial =====
    float sc0 = 0.f, sc1 = 0.f;        // s = 128p+lane, 128p+64+lane
#pragma unroll
    for (int c = 0; c < 4; ++c) {
      float4 qc = *(const float4*)&hqf[16 * h + 4 * c];
      if (t) {
        const float4 qm = ((const float4*)qmL)[(4 * h + c) * Sn + idx];  // broadcast
        qc.x += qm.x; qc.y += qm.y; qc.z += qm.z; qc.w += qm.w;
      }
      sc0 += qc.x*Kr[0][4*c] + qc.y*Kr[0][4*c+1] + qc.z*Kr[0][4*c+2] + qc.w*Kr[0][4*c+3];
      sc1 += qc.x*Kr[1][4*c] + qc.y*Kr[1][4*c+1] + qc.z*Kr[1][4*c+2] + qc.w*Kr[1][4*c+3];
    }
    const bool mk0 = (mreg >> (2 * p)) & 1u, mk1 = (mreg >> (2 * p + 1)) & 1u;
    sc0 = mk0 ? NEG_INF : sc0 * 0.25f;      // 1/sqrt(16)
    sc1 = mk1 ? NEG_INF : sc1 * 0.25f;
    float m = fmaxf(sc0, sc1);
#pragma unroll
    for (int off = 1; off < 64; off <<= 1) m = fmaxf(m, __shfl_xor(m, off));
    const float ev0 = mk0 ? 0.f : __expf(sc0 - m);   // explicit 0 avoids inf-inf
    const float ev1 = mk1 ? 0.f : __expf(sc1 - m);
    float ssum = ev0 + ev1;
#pragma unroll
    for (int off = 1; off < 64; off <<= 1) ssum += __shfl_xor(ssum, off);
    // unnormalized ctx partial, halving butterfly in 2 chunks of 8 (reg-lean)
#pragma unroll
    for (int ch = 0; ch < 2; ++ch) {
      float red[8];
#pragma unroll
      for (int d = 0; d < 8; ++d) red[d] = ev0 * Vr[0][8*ch+d] + ev1 * Vr[1][8*ch+d];
#pragma unroll
      for (int k = 0; k < 3; ++k) {
        const int off = 1 << k, hh = 4 >> k;
#pragma unroll
        for (int i = 0; i < 4; ++i) if (i < hh) {
          const bool up = (lane & off) != 0;
          const float send = up ? red[i] : red[i + hh];
          const float keep = up ? red[i + hh] : red[i];
          red[i] = keep + __shfl_xor(send, off);
        }
      }
      red[0] += __shfl_xor(red[0], 8);
      red[0] += __shfl_xor(red[0], 16);
      red[0] += __shfl_xor(red[0], 32);
      if (lane < 8) {
        const int dm3 = ((lane & 1) << 2) | (lane & 2) | ((lane & 4) >> 2);
        ctxpart[w][8 * ch + dm3] = red[0];
      }
    }
    if (lane == 0) { msA[w] = m; msS[w] = ssum; }
    __syncthreads();   // b1

    // ===== C: combine pair softmax + u partials over i-slice (registers) =====
    {
      const float m0 = msA[2 * h], m1 = msA[2 * h + 1];
      const float M = fmaxf(m0, m1);
      float c0 = __expf(m0 - M), c1 = __expf(m1 - M);     // exp(-inf)=0
      const float inv = 1.f / (c0 * msS[2 * h] + c1 * msS[2 * h + 1]);
      c0 *= inv; c1 *= inv;
      float u0 = 0.f, u1 = 0.f, u2 = 0.f, u3 = 0.f;
#pragma unroll
      for (int j = 0; j < 8; ++j) {
        const int d = (p << 3) + j;                       // ctx idx = 16h + d = 8w+j
        const float cx = c0 * ctxpart[2 * h][d] + c1 * ctxpart[2 * h + 1][d];
        u0 += cx * KPr[0][j]; u1 += cx * KPr[1][j];
        u2 += cx * KPr[2][j]; u3 += cx * KPr[3][j];
      }
      part[w * 256 +       lane] = u0;
      part[w * 256 +  64 + lane] = u1;
      part[w * 256 + 128 + lane] = u2;
      part[w * 256 + 192 + lane] = u3;
    }
    __syncthreads();   // b2

    // ===== D: finalize u = 10*tanh(dot/sqrt(128)) =====
    float uu = 0.f;
    if (tid < Sn) {
      float u = 0.f;
#pragma unroll
      for (int ww = 0; ww < 16; ++ww) u += part[ww * 256 + tid];
      const float e2 = __expf(u * 0.17677669529663687f);   // 2/sqrt(128)
      uu = 10.f - 20.f / (e2 + 1.f);
      uvals[tid] = uu;
    }
    __syncthreads();   // b3

    // ===== E: redundant per-wave argmax (no broadcast barrier needed) =====
    float bv = NEG_INF; int bi = 1 << 30;
    float vk[4];
#pragma unroll
    for (int k = 0; k < 4; ++k) {
      const int s = 64 * k + lane;
      const float v = ((mreg >> k) & 1u) ? NEG_INF : uvals[s];
      vk[k] = v;
      if (v > bv || (v == bv && s < bi)) { bv = v; bi = s; }
    }
#pragma unroll
    for (int off = 1; off < 64; off <<= 1) {
      const float ov = __shfl_xor(bv, off); const int oi = __shfl_xor(bi, off);
      if (ov > bv || (ov == bv && oi < bi)) { bv = ov; bi = oi; }
    }
    idx = bi;
    if ((idx & 63) == lane) mreg |= 1u << (idx >> 6);
    // global stores AFTER argmax: their vmcnt drain lands on next b1, off path
    if (tid < Sn) out[((size_t)b * Tn + t) * Sn + tid] = uu;  // raw logits
    if (w == 0) {
      float s2 = 0.f;
#pragma unroll
      for (int k = 0; k < 4; ++k) s2 += __expf(vk[k] - bv);   // exp(-inf)=0
#pragma unroll
      for (int off = 1; off < 64; off <<= 1) s2 += __shfl_xor(s2, off);
      if (lane == 0) {
        logp += __logf(s2);      // ce = log(sum(exp(u - max)))
        out[SOL_OFF + (size_t)b * Sn + t + 1] = (float)bi;
      }
    }

    if (t == 0) {     // hqf = qtop + first@Wq_bot (once; first = enc[b, idx0])
      if (tid < En) ebuf[tid] = enc[((size_t)b * Sn + idx) * En + tid];
      __syncthreads();
      {
        const int seg = tid >> 7, e = tid & 127;
        float pb = 0.f;
#pragma unroll
        for (int r = 0; r < 16; ++r)
          pb += ebuf[seg * 16 + r] * Wq[(size_t)(2 * En + seg * 16 + r) * En + e];
        part[seg * 256 + e] = pb;
      }
      __syncthreads();
      if (tid < En) {
        float acc2 = qtop[(size_t)b * En + tid];
#pragma unroll
        for (int sg = 0; sg < 8; ++sg) acc2 += part[sg * 256 + tid];
        hqf[tid] = acc2;
      }
      __syncthreads();
    }
  }
  if (tid == 0) out[LOGP_OFF + b] = logp;
}

// ---------------------------------------------------------------------------
extern "C" void kernel_launch(void* const* d_in, const int* in_sizes, int n_in,
                              void* d_out, int out_size, void* d_ws, size_t ws_size,
                              hipStream_t stream)
{
  const float* enc = (const float*)d_in[0];
  // d_in[1] demands, d_in[2] capacities: unused by the forward pass
  const float* vl  = (const float*)d_in[3];
  const float* vf  = (const float*)d_in[4];
  const float* Wq  = (const float*)d_in[5];
  const float* Wk  = (const float*)d_in[6];
  const float* Wv  = (const float*)d_in[7];
  const float* Wo  = (const float*)d_in[8];
  const float* Wp  = (const float*)d_in[9];
  float* out = (float*)d_out;

  float* ws    = (float*)d_ws;
  const size_t BSE = (size_t)Bn * Sn * En;
  float* K2    = ws;                  // [B][32][S][4]
  float* V2    = K2  + BSE;           // [B][32][S][4]
  float* QM    = V2  + BSE;           // [B][32][S][4]  enc@Wq_mid (g-major)
  float* KP2   = QM  + BSE;           // [B][32][S][4]  enc@(Wp@Wo^T)
  float* qtop  = KP2 + BSE;           // [B][E]
  float* qh0   = qtop + (size_t)Bn * En;   // [B][E]
  float* Wfold = qh0  + (size_t)Bn * En;   // [E][E]

  hipLaunchKernelGGL(hhat_kernel, dim3(Bn), dim3(En), 0, stream, enc, vl, vf, Wq, qtop, qh0);
  hipLaunchKernelGGL(wfold_kernel, dim3(En), dim3(En), 0, stream, Wp, Wo, Wfold);
  hipLaunchKernelGGL(proj_kernel, dim3(256), dim3(256), 0, stream,
                     enc, Wk, Wv, Wq, Wfold, K2, V2, QM, KP2);
  hipLaunchKernelGGL(decode_kernel, dim3(Bn), dim3(1024), 0, stream,
                     enc, Wq, K2, V2, KP2, QM, qtop, qh0, out);
}